// Round 10
// baseline (60.773 us; speedup 1.0000x reference)
//
#include <hip/hip_runtime.h>

#define P_NUM 40
#define N_VERT 128
#define H 256
#define W 256
#define BS 8
#define C_IN 64
#define PIX (H * W)
#define PIX4 (PIX / 4)         // 16384 vf4 per plane
#define CHUNKS 64              // 1024-px chunks per image
#define ASPLIT 4               // c-splits in fuse blocks
#define CPS (C_IN / ASPLIT)    // 16 channels per fuse block
#define ROWS_PER_BLK 4         // pnp scanlines per block
#define ESEG 16                // expand: segments per plane (1024 vf4 each)

typedef float vf2 __attribute__((ext_vector_type(2)));
typedef float vf4 __attribute__((ext_vector_type(4)));

// Kernel A: even-odd point-in-polygon rasterization -> BIT rows.
// One block per (polygon p, 4 scanlines); contour loaded to LDS once.
__global__ __launch_bounds__(256) void pnp_bits_kernel(
    const float* __restrict__ contour, unsigned int* __restrict__ bitws) {
    const int p = blockIdx.x;
    const int y0 = blockIdx.y * ROWS_PER_BLK;
    const int tid = threadIdx.x;

    __shared__ float sx[N_VERT];
    __shared__ float sy[N_VERT];
    __shared__ float xints[N_VERT];
    __shared__ int kcnt;

    if (tid < N_VERT) {
        const vf2 v = reinterpret_cast<const vf2*>(contour)[p * N_VERT + tid];
        sx[tid] = v.x;
        sy[tid] = v.y;
    }

    const float px = (float)tid;
    for (int r = 0; r < ROWS_PER_BLK; ++r) {
        const int y = y0 + r;
        if (tid == 0) kcnt = 0;
        __syncthreads();

        const float py = (float)y;
        if (tid < N_VERT) {
            const float y1 = sy[tid];
            const int e2 = (tid + 1) & (N_VERT - 1);
            const float y2 = sy[e2];
            const bool crosses = (y1 > py) != (y2 > py);  // exactly as reference
            if (crosses) {
                const float x1 = sx[tid];
                const float x2 = sx[e2];
                const float denom = (y2 == y1) ? 1.0f : (y2 - y1);
                // mul -> div -> add: no FMA contraction; IEEE f32, bit-exact.
                const float xint = (x2 - x1) * (py - y1) / denom + x1;
                const int slot = atomicAdd(&kcnt, 1);
                xints[slot] = xint;
            }
        }
        __syncthreads();

        const int K = kcnt;
        int cnt = 0;
        for (int k = 0; k < K; ++k) {
            cnt += (px < xints[k]) ? 1 : 0;
        }
        const unsigned long long b = __ballot(cnt & 1);
        if ((tid & 63) == 0) {
            *reinterpret_cast<unsigned long long*>(
                bitws + ((size_t)(p * H + y) << 3) + ((tid >> 6) << 1)) = b;
        }
        __syncthreads();
    }
}

__device__ __forceinline__ vf4 expand_bits(unsigned int word, int sh) {
    vf4 m;
    m.x = ((word >> (sh + 0)) & 1u) ? 1.0f : 0.0f;
    m.y = ((word >> (sh + 1)) & 1u) ? 1.0f : 0.0f;
    m.z = ((word >> (sh + 2)) & 1u) ? 1.0f : 0.0f;
    m.w = ((word >> (sh + 3)) & 1u) ? 1.0f : 0.0f;
    return m;
}

// Kernel B: block-specialized tail, one dispatch, coarse-grained.
//  type A (2048 blocks): (image, 1024-px chunk, c-quarter): OR the cn
//    bit-words once -> mx, stream 16 feature channels relu(mx*f+f), nt.
//  type B (1920 blocks): mask_batch bit-expand, 4 vf4 (64 B) per thread.
__global__ __launch_bounds__(256) void fuse_expand_kernel(
    const unsigned int* __restrict__ bitws, const float* __restrict__ feat,
    const int* __restrict__ ct_num, float* __restrict__ out_mask,
    float* __restrict__ out_cnn, int C) {
    const int FUSE_BLOCKS = BS * CHUNKS * ASPLIT;  // 2048
    const int bid = blockIdx.x;
    const int tid = threadIdx.x;

    if (bid < FUSE_BLOCKS) {
        const int split = bid & (ASPLIT - 1);
        const int chunk = (bid >> 2) & (CHUNKS - 1);
        const int i = bid >> 8;

        const int cn = ct_num[i];
        const int start = (i == 0) ? 0 : ct_num[i - 1];  // faithful: NOT cumsum

        const int qv = chunk * 256 + tid;   // vf4 index within image
        const int pix = qv << 2;
        const int y = pix >> 8;             // /W
        const int w = (pix & 255) >> 5;     // u32 word within row
        const int sh = pix & 31;

        // OR the bit-words once (u32 L1-broadcast hits)
        unsigned int orw = 0u;
        for (int j = 0; j < cn; ++j) {
            const int p = min(max(start + j, 0), P_NUM - 1);  // jnp.clip
            orw |= bitws[((size_t)(p * H + y) << 3) + w];
        }
        const vf4 mx = expand_bits(orw, sh);  // max over planes == OR of bits

        // 16 channels: load (static f[] - stays in VGPRs), fuse, nt-store
        const int cbase = split * CPS;
        vf4 f[CPS];
#pragma unroll
        for (int cc = 0; cc < CPS; ++cc) {
            const size_t idx = ((size_t)(i * C_IN + cbase + cc) << 14) + qv;
            f[cc] = reinterpret_cast<const vf4*>(feat)[idx];
        }
#pragma unroll
        for (int cc = 0; cc < CPS; ++cc) {
            const size_t idx = ((size_t)(i * C_IN + cbase + cc) << 14) + qv;
            vf4 r;
            // m in {0,1} exactly -> m*f+f == f or 2f exactly, FMA-insensitive.
            r.x = fmaxf(mx.x * f[cc].x + f[cc].x, 0.0f);
            r.y = fmaxf(mx.y * f[cc].y + f[cc].y, 0.0f);
            r.z = fmaxf(mx.z * f[cc].z + f[cc].z, 0.0f);
            r.w = fmaxf(mx.w * f[cc].w + f[cc].w, 0.0f);
            __builtin_nontemporal_store(r, reinterpret_cast<vf4*>(out_cnn) + idx);
        }
    } else {
        // expand: block = (i, j, 1024-vf4 segment); thread does 4 vf4 (64 B)
        const int b2 = bid - FUSE_BLOCKS;          // BS*C*ESEG blocks
        const int seg = b2 & (ESEG - 1);
        const int ij = b2 >> 4;
        const int i = ij / C;
        const int j = ij - i * C;

        const int cnv = ct_num[i];
        const int start = (i == 0) ? 0 : ct_num[i - 1];
        const int p = min(max(start + j, 0), P_NUM - 1);
        const bool valid = (j < cnv);

        const int qbase = seg * 1024;
#pragma unroll
        for (int s = 0; s < 4; ++s) {
            const int qv = qbase + s * 256 + tid;
            const int pix = qv << 2;
            const int y = pix >> 8;
            const int w = (pix & 255) >> 5;
            const int sh = pix & 31;

            vf4 m = {0.f, 0.f, 0.f, 0.f};
            if (valid) {
                m = expand_bits(bitws[((size_t)(p * H + y) << 3) + w], sh);
            }
            __builtin_nontemporal_store(
                m, reinterpret_cast<vf4*>(out_mask) + ((size_t)ij << 14) + qv);
        }
    }
}

extern "C" void kernel_launch(void* const* d_in, const int* in_sizes, int n_in,
                              void* d_out, int out_size, void* d_ws, size_t ws_size,
                              hipStream_t stream) {
    const float* contour = (const float*)d_in[0];  // [P, N, 2] f32
    const float* feat = (const float*)d_in[1];     // [BS, C_IN, H, W] f32
    const int* ct_num = (const int*)d_in[2];       // [BS] i32

    float* out = (float*)d_out;
    const int cnn_elems = BS * C_IN * PIX;
    const int C = (out_size - cnn_elems) / (BS * PIX);  // = max(ct_num)

    unsigned int* bitws = (unsigned int*)d_ws;     // [P, H, 8] u32 = 320 KB
    float* out_mask = out;
    float* out_cnn = out + (size_t)BS * C * PIX;

    hipLaunchKernelGGL(pnp_bits_kernel, dim3(P_NUM, H / ROWS_PER_BLK), dim3(256),
                       0, stream, contour, bitws);

    const int fuse_blocks = BS * CHUNKS * ASPLIT;          // 2048
    const int expand_blocks = BS * C * ESEG;               // e.g. 1920 (C=15)
    hipLaunchKernelGGL(fuse_expand_kernel, dim3(fuse_blocks + expand_blocks),
                       dim3(256), 0, stream, bitws, feat, ct_num, out_mask,
                       out_cnn, C);
}

// Round 11
// 56.833 us; speedup vs baseline: 1.0693x; 1.0693x over previous
//
#include <hip/hip_runtime.h>

#define P_NUM 40
#define N_VERT 128
#define H 256
#define W 256
#define BS 8
#define C_IN 64
#define PIX (H * W)
#define PIX4 (PIX / 4)         // 16384 vf4 per plane
#define CHUNKS 64              // 1024-px chunks per image
#define ASPLIT 8               // c-splits in fuse blocks
#define CPS (C_IN / ASPLIT)    // 8 channels per fuse block

typedef float vf2 __attribute__((ext_vector_type(2)));
typedef float vf4 __attribute__((ext_vector_type(4)));

// Kernel A: even-odd point-in-polygon rasterization -> BIT rows.
// One block per (polygon p, scanline y); 256 threads = one pixel column each.
// Row parity is emitted as 8 u32 words via __ballot (mask total = 320 KB).
__global__ __launch_bounds__(256) void pnp_bits_kernel(
    const float* __restrict__ contour, unsigned int* __restrict__ bitws) {
    const int p = blockIdx.x;
    const int y = blockIdx.y;
    const int tid = threadIdx.x;

    __shared__ float sx[N_VERT];
    __shared__ float sy[N_VERT];
    __shared__ float xints[N_VERT];
    __shared__ int kcnt;

    if (tid < N_VERT) {
        const vf2 v = reinterpret_cast<const vf2*>(contour)[p * N_VERT + tid];
        sx[tid] = v.x;
        sy[tid] = v.y;
    }
    if (tid == 0) kcnt = 0;
    __syncthreads();

    const float py = (float)y;
    if (tid < N_VERT) {
        const float y1 = sy[tid];
        const int e2 = (tid + 1) & (N_VERT - 1);
        const float y2 = sy[e2];
        const bool crosses = (y1 > py) != (y2 > py);  // exactly as reference
        if (crosses) {
            const float x1 = sx[tid];
            const float x2 = sx[e2];
            const float denom = (y2 == y1) ? 1.0f : (y2 - y1);
            // mul -> div -> add: no FMA contraction; IEEE f32 == XLA bit-for-bit.
            const float xint = (x2 - x1) * (py - y1) / denom + x1;
            const int slot = atomicAdd(&kcnt, 1);
            xints[slot] = xint;
        }
    }
    __syncthreads();

    const int K = kcnt;
    const float px = (float)tid;
    int cnt = 0;
    for (int k = 0; k < K; ++k) {
        cnt += (px < xints[k]) ? 1 : 0;  // broadcast LDS read, conflict-free
    }
    // parity bit -> ballot word; lane 0 of each wave stores 8 B.
    const unsigned long long b = __ballot(cnt & 1);
    if ((tid & 63) == 0) {
        // layout: bitws[(p*H + y)*8 + w], w = x/32 (little-endian u64 = w, w+1)
        *reinterpret_cast<unsigned long long*>(
            bitws + ((size_t)(p * H + y) << 3) + ((tid >> 6) << 1)) = b;
    }
}

__device__ __forceinline__ vf4 expand_bits(unsigned int word, int sh) {
    vf4 m;
    m.x = ((word >> (sh + 0)) & 1u) ? 1.0f : 0.0f;
    m.y = ((word >> (sh + 1)) & 1u) ? 1.0f : 0.0f;
    m.z = ((word >> (sh + 2)) & 1u) ? 1.0f : 0.0f;
    m.w = ((word >> (sh + 3)) & 1u) ? 1.0f : 0.0f;
    return m;
}

// Kernel B: block-specialized tail, one dispatch.
//  type A (first FUSE_BLOCKS): (image, 1024-px chunk, 8-channel split).
//    thread: OR the cn bit-words (u32 L1-broadcast loads) -> mx, then stream
//    8 feature channels: relu(mx*f + f), nt-stored. 4096 blocks.
//  type B (rest): mask_batch bit-expand. thread: 1 u32 load -> 4 floats,
//    nt-store; zeros for invalid j. BS*C*64 blocks.
__global__ __launch_bounds__(256) void fuse_expand_kernel(
    const unsigned int* __restrict__ bitws, const float* __restrict__ feat,
    const int* __restrict__ ct_num, float* __restrict__ out_mask,
    float* __restrict__ out_cnn, int C) {
    const int FUSE_BLOCKS = BS * CHUNKS * ASPLIT;  // 4096
    const int bid = blockIdx.x;
    const int tid = threadIdx.x;

    if (bid < FUSE_BLOCKS) {
        const int split = bid & (ASPLIT - 1);
        const int chunk = (bid >> 3) & (CHUNKS - 1);
        const int i = bid >> 9;

        const int cn = ct_num[i];
        const int start = (i == 0) ? 0 : ct_num[i - 1];  // faithful: NOT cumsum

        const int qv = chunk * 256 + tid;   // vf4 index within image
        const int pix = qv << 2;
        const int y = pix >> 8;             // /W
        const int w = (pix & 255) >> 5;     // u32 word within row
        const int sh = pix & 31;

        unsigned int orw = 0u;
        for (int j = 0; j < cn; ++j) {
            const int p = min(max(start + j, 0), P_NUM - 1);  // jnp.clip
            orw |= bitws[((size_t)(p * H + y) << 3) + w];     // L1-broadcast
        }
        const vf4 mx = expand_bits(orw, sh);  // max over planes == OR of bits

        const int cbase = split * CPS;
        for (int cc = 0; cc < CPS; ++cc) {
            // plane stride in vf4 units is PIX4 = 2^14
            const size_t idx = ((size_t)(i * C_IN + cbase + cc) << 14) + qv;
            const vf4 f = reinterpret_cast<const vf4*>(feat)[idx];
            vf4 r;
            // m in {0,1} exactly -> m*f+f == f or 2f exactly, FMA-insensitive.
            r.x = fmaxf(mx.x * f.x + f.x, 0.0f);
            r.y = fmaxf(mx.y * f.y + f.y, 0.0f);
            r.z = fmaxf(mx.z * f.z + f.z, 0.0f);
            r.w = fmaxf(mx.w * f.w + f.w, 0.0f);
            __builtin_nontemporal_store(r, reinterpret_cast<vf4*>(out_cnn) + idx);
        }
    } else {
        const int b2 = bid - FUSE_BLOCKS;          // BS*C*CHUNKS blocks
        const int chunk = b2 & (CHUNKS - 1);
        const int ij = b2 >> 6;
        const int i = ij / C;
        const int j = ij - i * C;

        const int qv = chunk * 256 + tid;
        const int pix = qv << 2;
        const int y = pix >> 8;
        const int w = (pix & 255) >> 5;
        const int sh = pix & 31;

        vf4 m = {0.f, 0.f, 0.f, 0.f};
        if (j < ct_num[i]) {
            const int start = (i == 0) ? 0 : ct_num[i - 1];
            const int p = min(max(start + j, 0), P_NUM - 1);
            m = expand_bits(bitws[((size_t)(p * H + y) << 3) + w], sh);
        }
        // plane stride in vf4 units is PIX4 = 2^14
        __builtin_nontemporal_store(
            m, reinterpret_cast<vf4*>(out_mask) + ((size_t)ij << 14) + qv);
    }
}

extern "C" void kernel_launch(void* const* d_in, const int* in_sizes, int n_in,
                              void* d_out, int out_size, void* d_ws, size_t ws_size,
                              hipStream_t stream) {
    const float* contour = (const float*)d_in[0];  // [P, N, 2] f32
    const float* feat = (const float*)d_in[1];     // [BS, C_IN, H, W] f32
    const int* ct_num = (const int*)d_in[2];       // [BS] i32

    float* out = (float*)d_out;
    const int cnn_elems = BS * C_IN * PIX;
    const int C = (out_size - cnn_elems) / (BS * PIX);  // = max(ct_num)

    unsigned int* bitws = (unsigned int*)d_ws;     // [P, H, 8] u32 = 320 KB
    float* out_mask = out;
    float* out_cnn = out + (size_t)BS * C * PIX;

    hipLaunchKernelGGL(pnp_bits_kernel, dim3(P_NUM, H), dim3(256), 0, stream,
                       contour, bitws);

    const int fuse_blocks = BS * CHUNKS * ASPLIT;          // 4096
    const int expand_blocks = BS * C * CHUNKS;             // e.g. 7680 (C=15)
    hipLaunchKernelGGL(fuse_expand_kernel, dim3(fuse_blocks + expand_blocks),
                       dim3(256), 0, stream, bitws, feat, ct_num, out_mask,
                       out_cnn, C);
}